// Round 10
// baseline (205.503 us; speedup 1.0000x reference)
//
#include <hip/hip_runtime.h>

#define CCH 128
#define SP  4096          // 64*64 spatial positions per (b,c)
#define BSTR 11           // G-band stride per sh (floats); odd -> bank spread
#define BROWS 10          // band rows rb in [0,10)
#define BSZ (64 * BSTR)   // 704 floats per band
#define GTOT (9 * BSZ)    // 6336 floats; +1 sentinel slot at g[0]
#define T16_OFF 65536     // byte offset of the u16 (s=8) table in d_ws
#define WT_OFFB 73728     // byte offset of transposed weights wT[c][o] in d_ws
#define CK 16             // conv K-chunk (c's per LDS tile)

__device__ __forceinline__ float sigmoidf_(float z) {
  return 1.0f / (1.0f + __expf(-z));
}

// Band-local gather offset for tap s at output wh: 1 + s*BSZ + sh*BSTR + rb,
// or 0 (sentinel -> g[0] = 0.0f) when the source pixel is out of bounds.
__device__ __forceinline__ int tap_off(int s, int wh) {
  int q  = (s << 12) + wh;     // flat index into torch's reinterpreted view
  int wi = q / 576;  int r  = q - wi * 576;
  int hi = r / 9;    int kk = r - hi * 9;
  int di = kk / 3,   dj = kk - di * 3;
  int sw = wi + di - 1, sh = hi + dj - 1;
  bool valid = ((unsigned)sw < 64u) & ((unsigned)sh < 64u);
  int wilo = (s * 64) / 9;     // first source row of band s
  return valid ? (1 + s * BSZ + sh * BSTR + (sw - wilo + 1)) : 0;
}

// One-time prep: packed gather tables (4xu32 pairs + u16) + weight transpose.
__global__ __launch_bounds__(256) void k_prep(
    const float* __restrict__ attn_w, unsigned* __restrict__ t32,
    unsigned short* __restrict__ t16, float* __restrict__ wT) {
  int i = blockIdx.x * 256 + threadIdx.x;   // 0 .. 5*4096 + 16384
  if (i < 4 * SP) {
    int j = i >> 12, wh = i & (SP - 1);
    unsigned lo = (unsigned)tap_off(2 * j, wh);
    unsigned hi = (unsigned)tap_off(2 * j + 1, wh);
    t32[(j << 12) + wh] = lo | (hi << 16);
  } else if (i < 5 * SP) {
    int wh = i & (SP - 1);
    t16[wh] = (unsigned short)tap_off(8, wh);
  } else {
    int j = i - 5 * SP;
    if (j < CCH * CCH) {
      int o = j >> 7, c = j & (CCH - 1);
      wT[c * CCH + o] = attn_w[j];   // coalesced read, scattered write (once)
    }
  }
}

// y[b,o,n] = sum_c attn_w[o][c]*x[b,c,n] -> d_out.
// Block = ALL 128 o x 64 n (x loaded from global exactly once, reused by all o).
// 256 thr = 4 waves; wave = 32 o x 64 n; thread = 8o x 4n (32 acc).
// K-chunks of 16 c staged in 4KB LDS: prefetch->reg, compute, barrier, write,
// barrier. Per c: 1 ds_read_b128 (2-way banks + lane broadcast) +
// 2 float4 wT loads (L1-hot) + 64 FMA-cycles.
template <bool PRET>
__global__ __launch_bounds__(256, 4) void k_conv(
    const float* __restrict__ x, const float* __restrict__ w,  // wT if PRET
    float* __restrict__ y) {
  __shared__ float xt[CK * 64];

  int b  = blockIdx.x >> 6;
  int ns = blockIdx.x & 63;
  int nbase = ns << 6;
  int lane = threadIdx.x & 63, wid = threadIdx.x >> 6;
  int o0 = (wid << 5) + ((lane >> 4) << 3);   // thread's 8 o's
  int n0 = (lane & 15) << 2;                  // thread's 4 n's (within slab)

  const float* xb = x + ((size_t)b << 19) + nbase;
  int scl = threadIdx.x >> 4, sfl = (threadIdx.x & 15) << 2;  // stage row/col

  float acc[8][4];
#pragma unroll
  for (int i = 0; i < 8; i++)
#pragma unroll
    for (int j = 0; j < 4; j++) acc[i][j] = 0.0f;

  // prologue: stage chunk 0
  float4 pf = *(const float4*)&xb[((size_t)scl << 12) + sfl];
  *(float4*)&xt[(scl << 6) + sfl] = pf;
  __syncthreads();

  for (int ch = 0; ch < CCH / CK; ch++) {
    if (ch + 1 < CCH / CK)   // prefetch next chunk into regs (hides under FMAs)
      pf = *(const float4*)&xb[((size_t)(((ch + 1) << 4) + scl) << 12) + sfl];

#pragma unroll
    for (int c = 0; c < CK; c++) {
      int cg = (ch << 4) + c;
      float4 xv = *(const float4*)&xt[(c << 6) + n0];
      float wsv[8];
      if (PRET) {
        float4 w0 = *(const float4*)&w[(cg << 7) + o0];
        float4 w1 = *(const float4*)&w[(cg << 7) + o0 + 4];
        wsv[0] = w0.x; wsv[1] = w0.y; wsv[2] = w0.z; wsv[3] = w0.w;
        wsv[4] = w1.x; wsv[5] = w1.y; wsv[6] = w1.z; wsv[7] = w1.w;
      } else {
#pragma unroll
        for (int i = 0; i < 8; i++) wsv[i] = w[((o0 + i) << 7) + cg];
      }
      float xs[4] = {xv.x, xv.y, xv.z, xv.w};
#pragma unroll
      for (int i = 0; i < 8; i++)
#pragma unroll
        for (int j = 0; j < 4; j++)
          acc[i][j] = fmaf(wsv[i], xs[j], acc[i][j]);
    }
    __syncthreads();
    if (ch + 1 < CCH / CK) {
      *(float4*)&xt[(scl << 6) + sfl] = pf;
      __syncthreads();
    }
  }

  float* yb = y + ((size_t)b << 19) + nbase + n0;
#pragma unroll
  for (int i = 0; i < 8; i++)
    *(float4*)&yb[(size_t)(o0 + i) << 12] =
        make_float4(acc[i][0], acc[i][1], acc[i][2], acc[i][3]);
}

// out[b,c,wh] = max_s G_s[src(s,wh)], G_s[p] = se[s]*x[p]*sigmoid(se[s]*y[p]+ab).
// Phase 1: G bands (1.4 sigmoids/output). Phase 2: 5 packed table loads +
// 9 ds_read_b32 + 9 fmax; OOB taps hit sentinel g[0] = 0 (no branches).
template <bool TBL>
__global__ __launch_bounds__(256) void k_attnmax(
    const float* __restrict__ x, float* __restrict__ yo,
    const float* __restrict__ se_param, const float* __restrict__ attn_b,
    const unsigned* __restrict__ t32, const unsigned short* __restrict__ t16) {
  __shared__ float g[GTOT + 1];
  __shared__ float se9[16];

  int bc = blockIdx.x;            // b*128 + c
  int c  = bc & (CCH - 1);
  const float* xp = x  + ((size_t)bc << 12);
  float*       yp = yo + ((size_t)bc << 12);

  if (threadIdx.x < 9) se9[threadIdx.x] = sigmoidf_(se_param[threadIdx.x]);
  if (threadIdx.x == 0) g[0] = 0.0f;
  float ab = attn_b[c];
  __syncthreads();

  // Phase 1: f -> (s, rb, sh); global source row rg = wilo(s) - 1 + rb.
  for (int f = threadIdx.x; f < 9 * 64 * BROWS; f += 256) {
    int s   = f / (64 * BROWS);
    int rem = f - s * (64 * BROWS);
    int rb  = rem >> 6, sh = rem & 63;
    int rg  = ((s * 64 * 58255) >> 19) - 1 + rb;   // wilo(s) = (s*64)/9
    float val = 0.0f;
    if ((unsigned)rg < 64u) {
      float se = se9[s];
      float xx = xp[(rg << 6) + sh];               // 256B coalesced rows
      float yy = yp[(rg << 6) + sh];
      float t  = __expf(-fmaf(se, yy, ab));
      val = se * xx * __builtin_amdgcn_rcpf(1.0f + t);
    }
    g[1 + s * BSZ + sh * BSTR + rb] = val;
  }
  __syncthreads();

  // Phase 2: gather + max; overwrite the y-plane with the result.
  for (int k = 0; k < 16; k++) {
    int wh = (k << 8) | threadIdx.x;
    float m;
    if (TBL) {
      unsigned p01 = t32[wh];
      unsigned p23 = t32[SP + wh];
      unsigned p45 = t32[2 * SP + wh];
      unsigned p67 = t32[3 * SP + wh];
      int p8 = t16[wh];
      float m0 = fmaxf(g[p01 & 0xffffu], g[p01 >> 16]);
      float m1 = fmaxf(g[p23 & 0xffffu], g[p23 >> 16]);
      float m2 = fmaxf(g[p45 & 0xffffu], g[p45 >> 16]);
      float m3 = fmaxf(g[p67 & 0xffffu], g[p67 >> 16]);
      m = fmaxf(fmaxf(fmaxf(m0, m1), fmaxf(m2, m3)), g[p8]);
    } else {
      m = -3.4e38f;
#pragma unroll
      for (int s = 0; s < 9; s++) m = fmaxf(m, g[tap_off(s, wh)]);
    }
    yp[wh] = m;
  }
}

extern "C" void kernel_launch(void* const* d_in, const int* in_sizes, int n_in,
                              void* d_out, int out_size, void* d_ws, size_t ws_size,
                              hipStream_t stream) {
  const float* x        = (const float*)d_in[0];
  const float* se_param = (const float*)d_in[1];
  const float* attn_w   = (const float*)d_in[2];
  const float* attn_b   = (const float*)d_in[3];
  float* out = (float*)d_out;

  int B = in_sizes[0] / (CCH * SP);
  unsigned* t32       = (unsigned*)d_ws;
  unsigned short* t16 = (unsigned short*)((char*)d_ws + T16_OFF);
  float* wT           = (float*)((char*)d_ws + WT_OFFB);
  bool use_ws = ws_size >= (size_t)(WT_OFFB + CCH * CCH * sizeof(float));

  if (use_ws) {
    k_prep<<<dim3(144), dim3(256), 0, stream>>>(attn_w, t32, t16, wT);
    k_conv<true><<<dim3(B * 64), dim3(256), 0, stream>>>(x, wT, out);
    k_attnmax<true><<<dim3(B * CCH), dim3(256), 0, stream>>>(
        x, out, se_param, attn_b, t32, t16);
  } else {
    k_conv<false><<<dim3(B * 64), dim3(256), 0, stream>>>(x, attn_w, out);
    k_attnmax<false><<<dim3(B * CCH), dim3(256), 0, stream>>>(
        x, out, se_param, attn_b, nullptr, nullptr);
  }
}

// Round 11
// 55.527 us; speedup vs baseline: 3.7010x; 3.7010x over previous
//
#include <hip/hip_runtime.h>

#define CCH 128
#define SP  4096          // 64*64 spatial positions per (b,c)
#define BSTR 11           // G-band stride per sh (floats); odd -> bank spread
#define BROWS 10          // band rows rb in [0,10)
#define BSZ (64 * BSTR)   // 704 floats per band
#define GTOT (9 * BSZ)    // 6336 floats; +1 sentinel slot at g[0]
#define T16_OFF 65536     // byte offset of the u16 (s=8) table in d_ws
#define WT_OFFB 73728     // byte offset of transposed weights wT[c][o] in d_ws
#define CK 16             // conv K-chunk (c's per LDS tile)

__device__ __forceinline__ float sigmoidf_(float z) {
  return 1.0f / (1.0f + __expf(-z));
}

// Band-local gather offset for tap s at output wh: 1 + s*BSZ + sh*BSTR + rb,
// or 0 (sentinel -> g[0] = 0.0f) when the source pixel is out of bounds.
__device__ __forceinline__ int tap_off(int s, int wh) {
  int q  = (s << 12) + wh;     // flat index into torch's reinterpreted view
  int wi = q / 576;  int r  = q - wi * 576;
  int hi = r / 9;    int kk = r - hi * 9;
  int di = kk / 3,   dj = kk - di * 3;
  int sw = wi + di - 1, sh = hi + dj - 1;
  bool valid = ((unsigned)sw < 64u) & ((unsigned)sh < 64u);
  int wilo = (s * 64) / 9;     // first source row of band s
  return valid ? (1 + s * BSZ + sh * BSTR + (sw - wilo + 1)) : 0;
}

// One-time prep: packed gather tables (4xu32 pairs + u16) + weight transpose.
__global__ __launch_bounds__(256) void k_prep(
    const float* __restrict__ attn_w, unsigned* __restrict__ t32,
    unsigned short* __restrict__ t16, float* __restrict__ wT) {
  int i = blockIdx.x * 256 + threadIdx.x;   // 0 .. 5*4096 + 16384
  if (i < 4 * SP) {
    int j = i >> 12, wh = i & (SP - 1);
    unsigned lo = (unsigned)tap_off(2 * j, wh);
    unsigned hi = (unsigned)tap_off(2 * j + 1, wh);
    t32[(j << 12) + wh] = lo | (hi << 16);
  } else if (i < 5 * SP) {
    int wh = i & (SP - 1);
    t16[wh] = (unsigned short)tap_off(8, wh);
  } else {
    int j = i - 5 * SP;
    if (j < CCH * CCH) {
      int o = j >> 7, c = j & (CCH - 1);
      wT[c * CCH + o] = attn_w[j];   // coalesced read, scattered write (once)
    }
  }
}

// y[b,o,n] = sum_c attn_w[o][c]*x[b,c,n] -> d_out.
// Block = ALL 128 o x 64 n (x loaded from global exactly once, reused by all o).
// 256 thr = 4 waves; wave = 32 o x 64 n; thread = 8o x 4n (32 acc).
// K-chunks of 16 c staged in 4KB LDS: prefetch->reg, compute, barrier, write,
// barrier. Per c: 1 ds_read_b128 (2-way banks + lane broadcast) +
// 2 float4 wT loads (L1-hot) + 64 FMA-cycles.
// __launch_bounds__(256,2): 256-VGPR cap. (256,4) forced a 64-VGPR cap ->
// 32 accumulators spilled to scratch: WRITE_SIZE 475 MB, 186 us (round 10).
template <bool PRET>
__global__ __launch_bounds__(256, 2) void k_conv(
    const float* __restrict__ x, const float* __restrict__ w,  // wT if PRET
    float* __restrict__ y) {
  __shared__ float xt[CK * 64];

  int b  = blockIdx.x >> 6;
  int ns = blockIdx.x & 63;
  int nbase = ns << 6;
  int lane = threadIdx.x & 63, wid = threadIdx.x >> 6;
  int o0 = (wid << 5) + ((lane >> 4) << 3);   // thread's 8 o's
  int n0 = (lane & 15) << 2;                  // thread's 4 n's (within slab)

  const float* xb = x + ((size_t)b << 19) + nbase;
  int scl = threadIdx.x >> 4, sfl = (threadIdx.x & 15) << 2;  // stage row/col

  float acc[8][4];
#pragma unroll
  for (int i = 0; i < 8; i++)
#pragma unroll
    for (int j = 0; j < 4; j++) acc[i][j] = 0.0f;

  // prologue: stage chunk 0
  float4 pf = *(const float4*)&xb[((size_t)scl << 12) + sfl];
  *(float4*)&xt[(scl << 6) + sfl] = pf;
  __syncthreads();

  for (int ch = 0; ch < CCH / CK; ch++) {
    if (ch + 1 < CCH / CK)   // prefetch next chunk into regs (hides under FMAs)
      pf = *(const float4*)&xb[((size_t)(((ch + 1) << 4) + scl) << 12) + sfl];

#pragma unroll
    for (int c = 0; c < CK; c++) {
      int cg = (ch << 4) + c;
      float4 xv = *(const float4*)&xt[(c << 6) + n0];
      float wsv[8];
      if (PRET) {
        float4 w0 = *(const float4*)&w[(cg << 7) + o0];
        float4 w1 = *(const float4*)&w[(cg << 7) + o0 + 4];
        wsv[0] = w0.x; wsv[1] = w0.y; wsv[2] = w0.z; wsv[3] = w0.w;
        wsv[4] = w1.x; wsv[5] = w1.y; wsv[6] = w1.z; wsv[7] = w1.w;
      } else {
#pragma unroll
        for (int i = 0; i < 8; i++) wsv[i] = w[((o0 + i) << 7) + cg];
      }
      float xs[4] = {xv.x, xv.y, xv.z, xv.w};
#pragma unroll
      for (int i = 0; i < 8; i++)
#pragma unroll
        for (int j = 0; j < 4; j++)
          acc[i][j] = fmaf(wsv[i], xs[j], acc[i][j]);
    }
    __syncthreads();
    if (ch + 1 < CCH / CK) {
      *(float4*)&xt[(scl << 6) + sfl] = pf;
      __syncthreads();
    }
  }

  float* yb = y + ((size_t)b << 19) + nbase + n0;
#pragma unroll
  for (int i = 0; i < 8; i++)
    *(float4*)&yb[(size_t)(o0 + i) << 12] =
        make_float4(acc[i][0], acc[i][1], acc[i][2], acc[i][3]);
}

// out[b,c,wh] = max_s G_s[src(s,wh)], G_s[p] = se[s]*x[p]*sigmoid(se[s]*y[p]+ab).
// Phase 1: G bands (1.4 sigmoids/output). Phase 2: 5 packed table loads +
// 9 ds_read_b32 + 9 fmax; OOB taps hit sentinel g[0] = 0 (no branches).
template <bool TBL>
__global__ __launch_bounds__(256) void k_attnmax(
    const float* __restrict__ x, float* __restrict__ yo,
    const float* __restrict__ se_param, const float* __restrict__ attn_b,
    const unsigned* __restrict__ t32, const unsigned short* __restrict__ t16) {
  __shared__ float g[GTOT + 1];
  __shared__ float se9[16];

  int bc = blockIdx.x;            // b*128 + c
  int c  = bc & (CCH - 1);
  const float* xp = x  + ((size_t)bc << 12);
  float*       yp = yo + ((size_t)bc << 12);

  if (threadIdx.x < 9) se9[threadIdx.x] = sigmoidf_(se_param[threadIdx.x]);
  if (threadIdx.x == 0) g[0] = 0.0f;
  float ab = attn_b[c];
  __syncthreads();

  // Phase 1: f -> (s, rb, sh); global source row rg = wilo(s) - 1 + rb.
  for (int f = threadIdx.x; f < 9 * 64 * BROWS; f += 256) {
    int s   = f / (64 * BROWS);
    int rem = f - s * (64 * BROWS);
    int rb  = rem >> 6, sh = rem & 63;
    int rg  = ((s * 64 * 58255) >> 19) - 1 + rb;   // wilo(s) = (s*64)/9
    float val = 0.0f;
    if ((unsigned)rg < 64u) {
      float se = se9[s];
      float xx = xp[(rg << 6) + sh];               // 256B coalesced rows
      float yy = yp[(rg << 6) + sh];
      float t  = __expf(-fmaf(se, yy, ab));
      val = se * xx * __builtin_amdgcn_rcpf(1.0f + t);
    }
    g[1 + s * BSZ + sh * BSTR + rb] = val;
  }
  __syncthreads();

  // Phase 2: gather + max; overwrite the y-plane with the result.
  for (int k = 0; k < 16; k++) {
    int wh = (k << 8) | threadIdx.x;
    float m;
    if (TBL) {
      unsigned p01 = t32[wh];
      unsigned p23 = t32[SP + wh];
      unsigned p45 = t32[2 * SP + wh];
      unsigned p67 = t32[3 * SP + wh];
      int p8 = t16[wh];
      float m0 = fmaxf(g[p01 & 0xffffu], g[p01 >> 16]);
      float m1 = fmaxf(g[p23 & 0xffffu], g[p23 >> 16]);
      float m2 = fmaxf(g[p45 & 0xffffu], g[p45 >> 16]);
      float m3 = fmaxf(g[p67 & 0xffffu], g[p67 >> 16]);
      m = fmaxf(fmaxf(fmaxf(m0, m1), fmaxf(m2, m3)), g[p8]);
    } else {
      m = -3.4e38f;
#pragma unroll
      for (int s = 0; s < 9; s++) m = fmaxf(m, g[tap_off(s, wh)]);
    }
    yp[wh] = m;
  }
}

extern "C" void kernel_launch(void* const* d_in, const int* in_sizes, int n_in,
                              void* d_out, int out_size, void* d_ws, size_t ws_size,
                              hipStream_t stream) {
  const float* x        = (const float*)d_in[0];
  const float* se_param = (const float*)d_in[1];
  const float* attn_w   = (const float*)d_in[2];
  const float* attn_b   = (const float*)d_in[3];
  float* out = (float*)d_out;

  int B = in_sizes[0] / (CCH * SP);
  unsigned* t32       = (unsigned*)d_ws;
  unsigned short* t16 = (unsigned short*)((char*)d_ws + T16_OFF);
  float* wT           = (float*)((char*)d_ws + WT_OFFB);
  bool use_ws = ws_size >= (size_t)(WT_OFFB + CCH * CCH * sizeof(float));

  if (use_ws) {
    k_prep<<<dim3(144), dim3(256), 0, stream>>>(attn_w, t32, t16, wT);
    k_conv<true><<<dim3(B * 64), dim3(256), 0, stream>>>(x, wT, out);
    k_attnmax<true><<<dim3(B * CCH), dim3(256), 0, stream>>>(
        x, out, se_param, attn_b, t32, t16);
  } else {
    k_conv<false><<<dim3(B * 64), dim3(256), 0, stream>>>(x, attn_w, out);
    k_attnmax<false><<<dim3(B * CCH), dim3(256), 0, stream>>>(
        x, out, se_param, attn_b, nullptr, nullptr);
  }
}

// Round 12
// 50.183 us; speedup vs baseline: 4.0951x; 1.1065x over previous
//
#include <hip/hip_runtime.h>

#define CCH 128
#define SP  4096          // 64*64 spatial positions per (b,c)
#define BSTR 11           // G-band stride per sh (floats); odd -> bank spread
#define BROWS 10          // band rows rb in [0,10)
#define BSZ (64 * BSTR)   // 704 floats per band
#define GTOT (9 * BSZ)    // 6336 floats; +1 sentinel slot at g[0]
#define T16_OFF 65536     // byte offset of the u16 (s=8) table in d_ws
#define WT_OFFB 73728     // byte offset of transposed weights wT[c][o] in d_ws

__device__ __forceinline__ float sigmoidf_(float z) {
  return 1.0f / (1.0f + __expf(-z));
}

// Band-local gather offset for tap s at output wh: 1 + s*BSZ + sh*BSTR + rb,
// or 0 (sentinel -> g[0] = 0.0f) when the source pixel is out of bounds.
__device__ __forceinline__ int tap_off(int s, int wh) {
  int q  = (s << 12) + wh;     // flat index into torch's reinterpreted view
  int wi = q / 576;  int r  = q - wi * 576;
  int hi = r / 9;    int kk = r - hi * 9;
  int di = kk / 3,   dj = kk - di * 3;
  int sw = wi + di - 1, sh = hi + dj - 1;
  bool valid = ((unsigned)sw < 64u) & ((unsigned)sh < 64u);
  int wilo = (s * 64) / 9;     // first source row of band s
  return valid ? (1 + s * BSZ + sh * BSTR + (sw - wilo + 1)) : 0;
}

// One-time prep: packed gather tables (uint4 = taps 0..7, u16 = tap 8) +
// weight transpose wT[c][o].
__global__ __launch_bounds__(256) void k_prep(
    const float* __restrict__ attn_w, unsigned* __restrict__ t32,
    unsigned short* __restrict__ t16, float* __restrict__ wT) {
  int i = blockIdx.x * 256 + threadIdx.x;   // 0 .. 4*SP + SP + 16384
  if (i < 4 * SP) {
    int wh = i >> 2, j = i & 3;             // t32[wh*4+j] -> taps 2j, 2j+1
    unsigned lo = (unsigned)tap_off(2 * j, wh);
    unsigned hi = (unsigned)tap_off(2 * j + 1, wh);
    t32[i] = lo | (hi << 16);
  } else if (i < 5 * SP) {
    int wh = i & (SP - 1);
    t16[wh] = (unsigned short)tap_off(8, wh);
  } else {
    int j = i - 5 * SP;
    if (j < CCH * CCH) {
      int o = j >> 7, c = j & (CCH - 1);
      wT[c * CCH + o] = attn_w[j];   // coalesced read, scattered write (once)
    }
  }
}

// y[b,o,n] = sum_c attn_w[o][c]*x[b,c,n] -> d_out.
// Block = 64o x 64n, 256 thr = 4 waves (wave = 16o x 64n), thread = 4o x 4n.
// Grid B*128 = 1024 -> 4 blocks/CU = 4 waves/SIMD (16 acc -> ~56 VGPR).
// 64-o weight slice (32 KB) staged once in LDS; main loop barrier-free:
// per c = 1 broadcast ds_read_b128 (banks {0,4,8,12}, conflict-free) +
// 1 coalesced 256B x float4 + 16 FMA; unroll 4 batches loads.
// Both oh-blocks of a slab are 64 apart in blockIdx -> same XCD L2 for x.
template <bool PRET>
__global__ __launch_bounds__(256) void k_conv(
    const float* __restrict__ x, const float* __restrict__ w,  // wT if PRET
    float* __restrict__ y) {
  __shared__ float wtl[CCH * 64];   // [c][local o], 32 KB

  int blk = blockIdx.x;
  int b   = blk >> 7;
  int oh  = (blk >> 6) & 1;
  int ns  = blk & 63;

  if (PRET) {
    // wT rows are 128 floats; copy the 64-float o-half of each row.
#pragma unroll
    for (int k = 0; k < 8; k++) {
      int f = (k << 8) + threadIdx.x;        // 0..2047 float4s
      int c = f >> 4, j = f & 15;
      float4 v = *(const float4*)&w[(c << 7) + (oh << 6) + (j << 2)];
      *(float4*)&wtl[(c << 6) + (j << 2)] = v;
    }
  } else {
    // fallback (no ws): in-kernel transpose, prologue-only
#pragma unroll
    for (int k = 0; k < 8; k++) {
      int f  = (k << 8) + threadIdx.x;       // 0..2047 float4s of attn_w slice
      int lo = f >> 5, c4 = (f & 31) << 2;
      float4 v = *(const float4*)&w[((oh << 6) + lo) * CCH + c4];
      wtl[(c4 + 0) * 64 + lo] = v.x;
      wtl[(c4 + 1) * 64 + lo] = v.y;
      wtl[(c4 + 2) * 64 + lo] = v.z;
      wtl[(c4 + 3) * 64 + lo] = v.w;
    }
  }
  __syncthreads();

  int lane = threadIdx.x & 63, wid = threadIdx.x >> 6;
  int lo0  = (wid << 4) + ((lane >> 4) << 2);   // local o: wave row + sub
  int n4   = (lane & 15) << 2;
  const float* xb = x + ((size_t)b << 19) + (ns << 6) + n4;

  float acc[4][4];
#pragma unroll
  for (int i = 0; i < 4; i++)
#pragma unroll
    for (int j = 0; j < 4; j++) acc[i][j] = 0.0f;

#pragma unroll 4
  for (int c = 0; c < CCH; c++) {
    float4 xv = *(const float4*)&xb[(size_t)c << 12];   // 256B coalesced
    float4 wv = *(const float4*)&wtl[(c << 6) + lo0];   // 4-addr broadcast
    float xs[4] = {xv.x, xv.y, xv.z, xv.w};
    float ws[4] = {wv.x, wv.y, wv.z, wv.w};
#pragma unroll
    for (int i = 0; i < 4; i++)
#pragma unroll
      for (int j = 0; j < 4; j++)
        acc[i][j] = fmaf(ws[i], xs[j], acc[i][j]);
  }

  int o0 = (oh << 6) + lo0;
  float* yb = y + ((size_t)b << 19) + (ns << 6) + n4;
#pragma unroll
  for (int i = 0; i < 4; i++)
    *(float4*)&yb[(size_t)(o0 + i) << 12] =
        make_float4(acc[i][0], acc[i][1], acc[i][2], acc[i][3]);
}

// out[b,c,wh] = max_s G_s[src(s,wh)], G_s[p] = se[s]*x[p]*sigmoid(se[s]*y[p]+ab).
// Phase 1: G bands (1.4 sigmoids/output). Phase 2: 1 uint4 + 1 u16 table load
// + 9 ds_read_b32 + 9 fmax; OOB taps hit sentinel g[0] = 0 (no branches).
template <bool TBL>
__global__ __launch_bounds__(256) void k_attnmax(
    const float* __restrict__ x, float* __restrict__ yo,
    const float* __restrict__ se_param, const float* __restrict__ attn_b,
    const uint4* __restrict__ t32, const unsigned short* __restrict__ t16) {
  __shared__ float g[GTOT + 1];
  __shared__ float se9[16];

  int bc = blockIdx.x;            // b*128 + c
  int c  = bc & (CCH - 1);
  const float* xp = x  + ((size_t)bc << 12);
  float*       yp = yo + ((size_t)bc << 12);

  if (threadIdx.x < 9) se9[threadIdx.x] = sigmoidf_(se_param[threadIdx.x]);
  if (threadIdx.x == 0) g[0] = 0.0f;
  float ab = attn_b[c];
  __syncthreads();

  // Phase 1: f -> (s, rb, sh); global source row rg = wilo(s) - 1 + rb.
  for (int f = threadIdx.x; f < 9 * 64 * BROWS; f += 256) {
    int s   = f / (64 * BROWS);
    int rem = f - s * (64 * BROWS);
    int rb  = rem >> 6, sh = rem & 63;
    int rg  = ((s * 64 * 58255) >> 19) - 1 + rb;   // wilo(s) = (s*64)/9
    float val = 0.0f;
    if ((unsigned)rg < 64u) {
      float se = se9[s];
      float xx = xp[(rg << 6) + sh];               // 256B coalesced rows
      float yy = yp[(rg << 6) + sh];
      float t  = __expf(-fmaf(se, yy, ab));
      val = se * xx * __builtin_amdgcn_rcpf(1.0f + t);
    }
    g[1 + s * BSZ + sh * BSTR + rb] = val;
  }
  __syncthreads();

  // Phase 2: gather + max; overwrite the y-plane with the result.
  for (int k = 0; k < 16; k++) {
    int wh = (k << 8) | threadIdx.x;
    float m;
    if (TBL) {
      uint4 p = t32[wh];                 // 16B coalesced: taps 0..7
      int p8  = t16[wh];
      float m0 = fmaxf(g[p.x & 0xffffu], g[p.x >> 16]);
      float m1 = fmaxf(g[p.y & 0xffffu], g[p.y >> 16]);
      float m2 = fmaxf(g[p.z & 0xffffu], g[p.z >> 16]);
      float m3 = fmaxf(g[p.w & 0xffffu], g[p.w >> 16]);
      m = fmaxf(fmaxf(fmaxf(m0, m1), fmaxf(m2, m3)), g[p8]);
    } else {
      m = -3.4e38f;
#pragma unroll
      for (int s = 0; s < 9; s++) m = fmaxf(m, g[tap_off(s, wh)]);
    }
    yp[wh] = m;
  }
}

extern "C" void kernel_launch(void* const* d_in, const int* in_sizes, int n_in,
                              void* d_out, int out_size, void* d_ws, size_t ws_size,
                              hipStream_t stream) {
  const float* x        = (const float*)d_in[0];
  const float* se_param = (const float*)d_in[1];
  const float* attn_w   = (const float*)d_in[2];
  const float* attn_b   = (const float*)d_in[3];
  float* out = (float*)d_out;

  int B = in_sizes[0] / (CCH * SP);
  unsigned* t32       = (unsigned*)d_ws;
  unsigned short* t16 = (unsigned short*)((char*)d_ws + T16_OFF);
  float* wT           = (float*)((char*)d_ws + WT_OFFB);
  bool use_ws = ws_size >= (size_t)(WT_OFFB + CCH * CCH * sizeof(float));

  if (use_ws) {
    k_prep<<<dim3(144), dim3(256), 0, stream>>>(attn_w, t32, t16, wT);
    k_conv<true><<<dim3(B * 128), dim3(256), 0, stream>>>(x, wT, out);
    k_attnmax<true><<<dim3(B * CCH), dim3(256), 0, stream>>>(
        x, out, se_param, attn_b, (const uint4*)t32, t16);
  } else {
    k_conv<false><<<dim3(B * 128), dim3(256), 0, stream>>>(x, attn_w, out);
    k_attnmax<false><<<dim3(B * CCH), dim3(256), 0, stream>>>(
        x, out, se_param, attn_b, nullptr, nullptr);
  }
}

// Round 13
// 37.857 us; speedup vs baseline: 5.4284x; 1.3256x over previous
//
#include <hip/hip_runtime.h>

#define CCH 128
#define SP  4096          // 64*64 spatial positions per (b,c)
#define BSTR 11           // G-band stride per sh (floats); odd -> bank spread
#define BROWS 10          // band rows rb in [0,10)
#define BSZ (64 * BSTR)   // 704 floats per band
#define GTOT (9 * BSZ)    // 6336 floats; +1 sentinel slot at g[0]
#define T16_OFF 65536     // byte offset of the u16 (s=8) table in d_ws
#define WT_OFFB 73728     // byte offset of bf16 weights w_bf[o][c] in d_ws
#define XTSTR 136         // LDS x_t halfword stride: 272B rows (16B-aligned, 2-way banks)

typedef __attribute__((ext_vector_type(8))) short bf16x8;   // 8 bf16 = 4 VGPRs
typedef __attribute__((ext_vector_type(4))) float f32x4;

__device__ __forceinline__ float sigmoidf_(float z) {
  return 1.0f / (1.0f + __expf(-z));
}

__device__ __forceinline__ unsigned short bf16rne(float f) {
  union { float f; unsigned u; } v; v.f = f;
  return (unsigned short)((v.u + 0x7fffu + ((v.u >> 16) & 1u)) >> 16);
}

// Band-local gather offset for tap s at output wh: 1 + s*BSZ + sh*BSTR + rb,
// or 0 (sentinel -> g[0] = 0.0f) when the source pixel is out of bounds.
__device__ __forceinline__ int tap_off(int s, int wh) {
  int q  = (s << 12) + wh;     // flat index into torch's reinterpreted view
  int wi = q / 576;  int r  = q - wi * 576;
  int hi = r / 9;    int kk = r - hi * 9;
  int di = kk / 3,   dj = kk - di * 3;
  int sw = wi + di - 1, sh = hi + dj - 1;
  bool valid = ((unsigned)sw < 64u) & ((unsigned)sh < 64u);
  int wilo = (s * 64) / 9;     // first source row of band s
  return valid ? (1 + s * BSZ + sh * BSTR + (sw - wilo + 1)) : 0;
}

// One-time prep: packed gather tables (uint4 = taps 0..7, u16 = tap 8) +
// bf16 weight conversion w_bf[o][c].
__global__ __launch_bounds__(256) void k_prep(
    const float* __restrict__ attn_w, unsigned* __restrict__ t32,
    unsigned short* __restrict__ t16, unsigned short* __restrict__ w_bf) {
  int i = blockIdx.x * 256 + threadIdx.x;   // 0 .. 5*SP + 16384
  if (i < 4 * SP) {
    int wh = i >> 2, j = i & 3;             // t32[wh*4+j] -> taps 2j, 2j+1
    unsigned lo = (unsigned)tap_off(2 * j, wh);
    unsigned hi = (unsigned)tap_off(2 * j + 1, wh);
    t32[i] = lo | (hi << 16);
  } else if (i < 5 * SP) {
    int wh = i & (SP - 1);
    t16[wh] = (unsigned short)tap_off(8, wh);
  } else {
    int j = i - 5 * SP;
    if (j < CCH * CCH) w_bf[j] = bf16rne(attn_w[j]);
  }
}

// y[b,o,n] = sum_c w[o][c]*x[b,c,n] -> d_out, via MFMA bf16 (K=128 exact fp32 acc).
// Block = 128o x 64n, 256 thr = 4 waves; wave = 32o x 64n = 2 o-tiles x 4 n-tiles.
// x tile (128c x 64n fp32) -> bf16 LDS x_t[n][k], stride 136 hw (2-way banks).
// A-frags (w) in registers from global (L2-hot 32KB); B-frags: ds_read_b128.
// A/B use the SAME k-slot indexing -> result invariant to HW k-permutation.
// C/D mapping (verified): col = lane&15 (n), row = (lane>>4)*4 + reg (o).
__global__ __launch_bounds__(256) void k_conv(
    const float* __restrict__ x, const unsigned short* __restrict__ w_bf,
    float* __restrict__ y) {
  __shared__ unsigned short x_t[64 * XTSTR];   // 17408 B

  int b  = blockIdx.x >> 6;
  int nb = blockIdx.x & 63;
  int lane = threadIdx.x & 63, wv = threadIdx.x >> 6;

  // A-fragments: wave wv owns o in [wv*32, wv*32+32): 2 o-tiles x 4 k-steps.
  // lane l holds A[o = ot*16 + (l&15)][k = ks*32 + (l>>4)*8 .. +7] (16B row chunk).
  bf16x8 afrag[2][4];
#pragma unroll
  for (int ot = 0; ot < 2; ot++)
#pragma unroll
    for (int ks = 0; ks < 4; ks++) {
      int o = (wv << 5) + (ot << 4) + (lane & 15);
      int k = (ks << 5) + ((lane >> 4) << 3);
      afrag[ot][ks] = *(const bf16x8*)&w_bf[(o << 7) + k];
    }

  // Stage x tile -> bf16 transposed LDS. Thread: 8 groups x (4 c-consecutive
  // values at one n). Loads: dword, 16-lane-contiguous n (64B segments).
  // Writes: ds_write_b64, banks 4n+c/2 -> lanes l,l+8 share (2-way, free).
  const float* xpb = x + ((size_t)b << 19) + (nb << 6);
#pragma unroll
  for (int g = 0; g < 8; g++) {
    int n  = (threadIdx.x & 15) + ((g & 3) << 4);
    int c0 = ((threadIdx.x >> 4) << 2) + ((g >> 2) << 6);
    float f0 = xpb[((size_t)(c0 + 0) << 12) + n];
    float f1 = xpb[((size_t)(c0 + 1) << 12) + n];
    float f2 = xpb[((size_t)(c0 + 2) << 12) + n];
    float f3 = xpb[((size_t)(c0 + 3) << 12) + n];
    union { unsigned short s[2]; unsigned u; } p0, p1;
    p0.s[0] = bf16rne(f0); p0.s[1] = bf16rne(f1);
    p1.s[0] = bf16rne(f2); p1.s[1] = bf16rne(f3);
    *(uint2*)&x_t[n * XTSTR + c0] = make_uint2(p0.u, p1.u);
  }
  __syncthreads();

  f32x4 acc[2][4] = {};
#pragma unroll
  for (int ks = 0; ks < 4; ks++) {
    bf16x8 bfrag[4];
#pragma unroll
    for (int nt = 0; nt < 4; nt++) {
      int n = (nt << 4) + (lane & 15);
      int k = (ks << 5) + ((lane >> 4) << 3);
      bfrag[nt] = *(const bf16x8*)&x_t[n * XTSTR + k];   // ds_read_b128
    }
#pragma unroll
    for (int ot = 0; ot < 2; ot++)
#pragma unroll
      for (int nt = 0; nt < 4; nt++)
        acc[ot][nt] = __builtin_amdgcn_mfma_f32_16x16x32_bf16(
            afrag[ot][ks], bfrag[nt], acc[ot][nt], 0, 0, 0);
  }

  // Epilogue: lane stores acc[ot][nt][r] to y[o][n], o = base + (lane>>4)*4 + r.
  float* yb = y + ((size_t)b << 19) + (nb << 6);
#pragma unroll
  for (int ot = 0; ot < 2; ot++) {
    int ob = (wv << 5) + (ot << 4) + ((lane >> 4) << 2);
#pragma unroll
    for (int nt = 0; nt < 4; nt++) {
      int n = (nt << 4) + (lane & 15);
#pragma unroll
      for (int r = 0; r < 4; r++)
        yb[((size_t)(ob + r) << 12) + n] = acc[ot][nt][r];
    }
  }
}

// Fallback conv (no workspace): R12's VALU version, LDS-staged weight slice.
__global__ __launch_bounds__(256) void k_conv_valu(
    const float* __restrict__ x, const float* __restrict__ w,
    float* __restrict__ y) {
  __shared__ float wtl[CCH * 64];
  int blk = blockIdx.x;
  int b = blk >> 7, oh = (blk >> 6) & 1, ns = blk & 63;
#pragma unroll
  for (int k = 0; k < 8; k++) {
    int f  = (k << 8) + threadIdx.x;
    int lo = f >> 5, c4 = (f & 31) << 2;
    float4 v = *(const float4*)&w[((oh << 6) + lo) * CCH + c4];
    wtl[(c4 + 0) * 64 + lo] = v.x;
    wtl[(c4 + 1) * 64 + lo] = v.y;
    wtl[(c4 + 2) * 64 + lo] = v.z;
    wtl[(c4 + 3) * 64 + lo] = v.w;
  }
  __syncthreads();
  int lane = threadIdx.x & 63, wid = threadIdx.x >> 6;
  int lo0 = (wid << 4) + ((lane >> 4) << 2);
  int n4  = (lane & 15) << 2;
  const float* xb = x + ((size_t)b << 19) + (ns << 6) + n4;
  float acc[4][4];
#pragma unroll
  for (int i = 0; i < 4; i++)
#pragma unroll
    for (int j = 0; j < 4; j++) acc[i][j] = 0.0f;
#pragma unroll 4
  for (int c = 0; c < CCH; c++) {
    float4 xv = *(const float4*)&xb[(size_t)c << 12];
    float4 wv = *(const float4*)&wtl[(c << 6) + lo0];
    float xs[4] = {xv.x, xv.y, xv.z, xv.w};
    float ws[4] = {wv.x, wv.y, wv.z, wv.w};
#pragma unroll
    for (int i = 0; i < 4; i++)
#pragma unroll
      for (int j = 0; j < 4; j++) acc[i][j] = fmaf(ws[i], xs[j], acc[i][j]);
  }
  float* yb = y + ((size_t)b << 19) + (ns << 6) + n4;
#pragma unroll
  for (int i = 0; i < 4; i++)
    *(float4*)&yb[(size_t)((oh << 6) + lo0 + i) << 12] =
        make_float4(acc[i][0], acc[i][1], acc[i][2], acc[i][3]);
}

// out[b,c,wh] = max_s G_s[src(s,wh)], G_s[p] = se[s]*x[p]*sigmoid(se[s]*y[p]+ab).
// Phase 1: G bands (1.4 sigmoids/output). Phase 2: 1 uint4 + 1 u16 table load
// + 9 ds_read_b32 + 9 fmax; OOB taps hit sentinel g[0] = 0 (no branches).
template <bool TBL>
__global__ __launch_bounds__(256) void k_attnmax(
    const float* __restrict__ x, float* __restrict__ yo,
    const float* __restrict__ se_param, const float* __restrict__ attn_b,
    const uint4* __restrict__ t32, const unsigned short* __restrict__ t16) {
  __shared__ float g[GTOT + 1];
  __shared__ float se9[16];

  int bc = blockIdx.x;            // b*128 + c
  int c  = bc & (CCH - 1);
  const float* xp = x  + ((size_t)bc << 12);
  float*       yp = yo + ((size_t)bc << 12);

  if (threadIdx.x < 9) se9[threadIdx.x] = sigmoidf_(se_param[threadIdx.x]);
  if (threadIdx.x == 0) g[0] = 0.0f;
  float ab = attn_b[c];
  __syncthreads();

  // Phase 1: f -> (s, rb, sh); global source row rg = wilo(s) - 1 + rb.
  for (int f = threadIdx.x; f < 9 * 64 * BROWS; f += 256) {
    int s   = f / (64 * BROWS);
    int rem = f - s * (64 * BROWS);
    int rb  = rem >> 6, sh = rem & 63;
    int rg  = ((s * 64 * 58255) >> 19) - 1 + rb;   // wilo(s) = (s*64)/9
    float val = 0.0f;
    if ((unsigned)rg < 64u) {
      float se = se9[s];
      float xx = xp[(rg << 6) + sh];               // 256B coalesced rows
      float yy = yp[(rg << 6) + sh];
      float t  = __expf(-fmaf(se, yy, ab));
      val = se * xx * __builtin_amdgcn_rcpf(1.0f + t);
    }
    g[1 + s * BSZ + sh * BSTR + rb] = val;
  }
  __syncthreads();

  // Phase 2: gather + max; overwrite the y-plane with the result.
  for (int k = 0; k < 16; k++) {
    int wh = (k << 8) | threadIdx.x;
    float m;
    if (TBL) {
      uint4 p = t32[wh];                 // 16B coalesced: taps 0..7
      int p8  = t16[wh];
      float m0 = fmaxf(g[p.x & 0xffffu], g[p.x >> 16]);
      float m1 = fmaxf(g[p.y & 0xffffu], g[p.y >> 16]);
      float m2 = fmaxf(g[p.z & 0xffffu], g[p.z >> 16]);
      float m3 = fmaxf(g[p.w & 0xffffu], g[p.w >> 16]);
      m = fmaxf(fmaxf(fmaxf(m0, m1), fmaxf(m2, m3)), g[p8]);
    } else {
      m = -3.4e38f;
#pragma unroll
      for (int s = 0; s < 9; s++) m = fmaxf(m, g[tap_off(s, wh)]);
    }
    yp[wh] = m;
  }
}

extern "C" void kernel_launch(void* const* d_in, const int* in_sizes, int n_in,
                              void* d_out, int out_size, void* d_ws, size_t ws_size,
                              hipStream_t stream) {
  const float* x        = (const float*)d_in[0];
  const float* se_param = (const float*)d_in[1];
  const float* attn_w   = (const float*)d_in[2];
  const float* attn_b   = (const float*)d_in[3];
  float* out = (float*)d_out;

  int B = in_sizes[0] / (CCH * SP);
  unsigned* t32        = (unsigned*)d_ws;
  unsigned short* t16  = (unsigned short*)((char*)d_ws + T16_OFF);
  unsigned short* w_bf = (unsigned short*)((char*)d_ws + WT_OFFB);
  bool use_ws = ws_size >= (size_t)(WT_OFFB + CCH * CCH * sizeof(unsigned short));

  if (use_ws) {
    k_prep<<<dim3(144), dim3(256), 0, stream>>>(attn_w, t32, t16, w_bf);
    k_conv<<<dim3(B * 64), dim3(256), 0, stream>>>(x, w_bf, out);
    k_attnmax<true><<<dim3(B * CCH), dim3(256), 0, stream>>>(
        x, out, se_param, attn_b, (const uint4*)t32, t16);
  } else {
    k_conv_valu<<<dim3(B * 128), dim3(256), 0, stream>>>(x, attn_w, out);
    k_attnmax<false><<<dim3(B * CCH), dim3(256), 0, stream>>>(
        x, out, se_param, attn_b, nullptr, nullptr);
  }
}

// Round 14
// 31.241 us; speedup vs baseline: 6.5780x; 1.2118x over previous
//
#include <hip/hip_runtime.h>

#define CCH 128
#define SP  4096          // 64*64 spatial positions per (b,c)
#define BROWS 10          // band rows rb in [0,10)
#define RSTR 68           // g rb-stride (floats): banks 4*rb -> conflict-free b128
#define BSZ2 (BROWS * RSTR)  // 680 floats per band
#define GOFF 16           // g data starts at 16 (64B-aligned); g[0] = sentinel 0
#define GTOT (GOFF + 9 * BSZ2)   // 6136 floats = 24.5 KB
#define T16_OFF 65536     // byte offset of the u16 (s=8) table in d_ws
#define TBLK 80           // table-generator blocks fused into conv grid
#define XTSTR 136         // LDS x_t halfword stride (272B rows)

typedef __attribute__((ext_vector_type(8))) short bf16x8;   // 8 bf16 = 4 VGPRs
typedef __attribute__((ext_vector_type(4))) float f32x4;

__device__ __forceinline__ float sigmoidf_(float z) {
  return 1.0f / (1.0f + __expf(-z));
}

__device__ __forceinline__ unsigned short bf16rne(float f) {
  union { float f; unsigned u; } v; v.f = f;
  return (unsigned short)((v.u + 0x7fffu + ((v.u >> 16) & 1u)) >> 16);
}

// Band-local gather offset for tap s at output wh (g layout [s][rb][sh]):
// GOFF + s*680 + rb*68 + sh, or 0 (sentinel g[0]=0) when source is OOB.
__device__ __forceinline__ int tap_off(int s, int wh) {
  int q  = (s << 12) + wh;     // flat index into torch's reinterpreted view
  int wi = q / 576;  int r  = q - wi * 576;
  int hi = r / 9;    int kk = r - hi * 9;
  int di = kk / 3,   dj = kk - di * 3;
  int sw = wi + di - 1, sh = hi + dj - 1;
  bool valid = ((unsigned)sw < 64u) & ((unsigned)sh < 64u);
  int wilo = (s * 64) / 9;     // first source row of band s
  int rb = sw - wilo + 1;      // in [0,10) for valid sw
  return valid ? (GOFF + s * BSZ2 + rb * RSTR + sh) : 0;
}

// Fused: blocks [0,TBLK) generate gather tables; blocks [TBLK,..) do the conv.
// Conv: y[b,o,n] = sum_c w[o][c]*x[b,c,n] via mfma_f32_16x16x32_bf16.
// Block = 128o x 32n, 4 waves; wave = 32o x 32n = 2 o-tiles x 2 n-tiles.
// Grid B*128(+80) -> 4 blocks/CU = 16 waves/CU (LDS 8.7KB) for latency hiding.
// A-frags converted in-kernel from fp32 attn_w (no prep dispatch, no w_bf).
// A/B share the same k-slot indexing -> invariant to HW k-permutation.
// C/D mapping (verified m89): col = lane&15 (n), row = (lane>>4)*4 + reg (o).
template <bool WS>
__global__ __launch_bounds__(256) void k_conv(
    const float* __restrict__ x, const float* __restrict__ attn_w,
    float* __restrict__ y, unsigned* __restrict__ t32,
    unsigned short* __restrict__ t16) {
  int bid = blockIdx.x;
  if (WS) {
    if (bid < TBLK) {   // table generation: 20480 entries, one per thread
      int i = bid * 256 + threadIdx.x;
      if (i < 4 * SP) {
        int wh = i >> 2, j = i & 3;         // t32[wh*4+j] -> taps 2j, 2j+1
        unsigned lo = (unsigned)tap_off(2 * j, wh);
        unsigned hi = (unsigned)tap_off(2 * j + 1, wh);
        t32[i] = lo | (hi << 16);
      } else if (i < 5 * SP) {
        int wh = i & (SP - 1);
        t16[wh] = (unsigned short)tap_off(8, wh);
      }
      return;
    }
    bid -= TBLK;
  }

  __shared__ unsigned short x_t[32 * XTSTR];   // 8704 B

  int b  = bid >> 7;
  int nb = bid & 127;                          // 32n slab
  int lane = threadIdx.x & 63, wv = threadIdx.x >> 6;

  // Issue staging loads first (16 scalar dwords; lanes 0-31 = 128B segments).
  const float* xpb = x + ((size_t)b << 19) + (nb << 5);
  int n_st  = threadIdx.x & 31;
  int c_st  = (threadIdx.x >> 5) << 2;
  float xv[16];
#pragma unroll
  for (int g = 0; g < 4; g++) {
    int c0 = c_st + (g << 5);
#pragma unroll
    for (int i = 0; i < 4; i++)
      xv[g * 4 + i] = xpb[((size_t)(c0 + i) << 12) + n_st];
  }

  // A-fragments from fp32 w (L2-hot 64KB): lane l holds
  // A[o = ot*16 + (l&15)][k = ks*32 + (l>>4)*8 .. +7], converted to bf16.
  bf16x8 afrag[2][4];
#pragma unroll
  for (int ot = 0; ot < 2; ot++)
#pragma unroll
    for (int ks = 0; ks < 4; ks++) {
      int o = (wv << 5) + (ot << 4) + (lane & 15);
      int k = (ks << 5) + ((lane >> 4) << 3);
      const float4* wp = (const float4*)&attn_w[(o << 7) + k];
      float4 a0 = wp[0], a1 = wp[1];
      bf16x8 f;
      f[0] = (short)bf16rne(a0.x); f[1] = (short)bf16rne(a0.y);
      f[2] = (short)bf16rne(a0.z); f[3] = (short)bf16rne(a0.w);
      f[4] = (short)bf16rne(a1.x); f[5] = (short)bf16rne(a1.y);
      f[6] = (short)bf16rne(a1.z); f[7] = (short)bf16rne(a1.w);
      afrag[ot][ks] = f;
    }

  // Convert + write staged x into transposed bf16 LDS x_t[n][k].
#pragma unroll
  for (int g = 0; g < 4; g++) {
    int c0 = c_st + (g << 5);
    union { unsigned short s[2]; unsigned u; } p0, p1;
    p0.s[0] = bf16rne(xv[g * 4 + 0]); p0.s[1] = bf16rne(xv[g * 4 + 1]);
    p1.s[0] = bf16rne(xv[g * 4 + 2]); p1.s[1] = bf16rne(xv[g * 4 + 3]);
    *(uint2*)&x_t[n_st * XTSTR + c0] = make_uint2(p0.u, p1.u);
  }
  __syncthreads();

  f32x4 acc[2][2] = {};
#pragma unroll
  for (int ks = 0; ks < 4; ks++) {
    bf16x8 bfrag[2];
#pragma unroll
    for (int nt = 0; nt < 2; nt++) {
      int n = (nt << 4) + (lane & 15);
      int k = (ks << 5) + ((lane >> 4) << 3);
      bfrag[nt] = *(const bf16x8*)&x_t[n * XTSTR + k];   // ds_read_b128
    }
#pragma unroll
    for (int ot = 0; ot < 2; ot++)
#pragma unroll
      for (int nt = 0; nt < 2; nt++)
        acc[ot][nt] = __builtin_amdgcn_mfma_f32_16x16x32_bf16(
            afrag[ot][ks], bfrag[nt], acc[ot][nt], 0, 0, 0);
  }

  // Epilogue: acc[ot][nt][r] -> y[o][n], o = base + (lane>>4)*4 + r.
  float* yb = y + ((size_t)b << 19) + (nb << 5);
#pragma unroll
  for (int ot = 0; ot < 2; ot++) {
    int ob = (wv << 5) + (ot << 4) + ((lane >> 4) << 2);
#pragma unroll
    for (int nt = 0; nt < 2; nt++) {
      int n = (nt << 4) + (lane & 15);
#pragma unroll
      for (int r = 0; r < 4; r++)
        yb[((size_t)(ob + r) << 12) + n] = acc[ot][nt][r];
    }
  }
}

// out[b,c,wh] = max_s G_s[src(s,wh)], G_s[p] = se[s]*x[p]*sigmoid(se[s]*y[p]+ab).
// Phase 1: G bands, float4 loads + one ds_write_b128 per 4 values
// (rb-stride 68 -> conflict-free). Phase 2: 1 uint4 + 1 u16 table load +
// 9 ds_read_b32 (9-lane broadcast groups) + 9 fmax; OOB -> sentinel g[0]=0.
template <bool TBL>
__global__ __launch_bounds__(256) void k_attnmax(
    const float* __restrict__ x, float* __restrict__ yo,
    const float* __restrict__ se_param, const float* __restrict__ attn_b,
    const uint4* __restrict__ t32, const unsigned short* __restrict__ t16) {
  __shared__ float g[GTOT];
  __shared__ float se9[16];

  int bc = blockIdx.x;            // b*128 + c
  int c  = bc & (CCH - 1);
  const float* xp = x  + ((size_t)bc << 12);
  float*       yp = yo + ((size_t)bc << 12);

  if (threadIdx.x < 9) se9[threadIdx.x] = sigmoidf_(se_param[threadIdx.x]);
  if (threadIdx.x == 0) g[0] = 0.0f;
  float ab = attn_b[c];
  __syncthreads();

  // Phase 1: 1440 float4 units -> (s, rb, sh0). Source row rg = wilo(s)-1+rb.
  for (int f = threadIdx.x; f < 9 * BROWS * 16; f += 256) {
    int s   = f / 160;
    int rem = f - s * 160;
    int rb  = rem >> 4, sh0 = (rem & 15) << 2;
    int rg  = ((s * 64 * 58255) >> 19) - 1 + rb;   // wilo(s) = (s*64)/9
    float4 gv = make_float4(0.0f, 0.0f, 0.0f, 0.0f);
    if ((unsigned)rg < 64u) {
      float se = se9[s];
      float4 xx = *(const float4*)&xp[(rg << 6) + sh0];   // 1KB/wave coalesced
      float4 yy = *(const float4*)&yp[(rg << 6) + sh0];
      gv.x = se * xx.x * sigmoidf_(fmaf(se, yy.x, ab));
      gv.y = se * xx.y * sigmoidf_(fmaf(se, yy.y, ab));
      gv.z = se * xx.z * sigmoidf_(fmaf(se, yy.z, ab));
      gv.w = se * xx.w * sigmoidf_(fmaf(se, yy.w, ab));
    }
    *(float4*)&g[GOFF + s * BSZ2 + rb * RSTR + sh0] = gv;  // b128, 16B-aligned
  }
  __syncthreads();

  // Phase 2: gather + max; overwrite the y-plane with the result.
  for (int k = 0; k < 16; k++) {
    int wh = (k << 8) | threadIdx.x;
    float m;
    if (TBL) {
      uint4 p = t32[wh];                 // 16B coalesced: taps 0..7
      int p8  = t16[wh];
      float m0 = fmaxf(g[p.x & 0xffffu], g[p.x >> 16]);
      float m1 = fmaxf(g[p.y & 0xffffu], g[p.y >> 16]);
      float m2 = fmaxf(g[p.z & 0xffffu], g[p.z >> 16]);
      float m3 = fmaxf(g[p.w & 0xffffu], g[p.w >> 16]);
      m = fmaxf(fmaxf(fmaxf(m0, m1), fmaxf(m2, m3)), g[p8]);
    } else {
      m = 0.0f;
#pragma unroll
      for (int s = 0; s < 9; s++) m = fmaxf(m, g[tap_off(s, wh)]);
    }
    yp[wh] = m;
  }
}

extern "C" void kernel_launch(void* const* d_in, const int* in_sizes, int n_in,
                              void* d_out, int out_size, void* d_ws, size_t ws_size,
                              hipStream_t stream) {
  const float* x        = (const float*)d_in[0];
  const float* se_param = (const float*)d_in[1];
  const float* attn_w   = (const float*)d_in[2];
  const float* attn_b   = (const float*)d_in[3];
  float* out = (float*)d_out;

  int B = in_sizes[0] / (CCH * SP);
  unsigned* t32       = (unsigned*)d_ws;
  unsigned short* t16 = (unsigned short*)((char*)d_ws + T16_OFF);
  bool use_ws = ws_size >= (size_t)(T16_OFF + SP * sizeof(unsigned short));

  if (use_ws) {
    k_conv<true><<<dim3(TBLK + B * 128), dim3(256), 0, stream>>>(
        x, attn_w, out, t32, t16);
    k_attnmax<true><<<dim3(B * CCH), dim3(256), 0, stream>>>(
        x, out, se_param, attn_b, (const uint4*)t32, t16);
  } else {
    k_conv<false><<<dim3(B * 128), dim3(256), 0, stream>>>(
        x, attn_w, out, nullptr, nullptr);
    k_attnmax<false><<<dim3(B * CCH), dim3(256), 0, stream>>>(
        x, out, se_param, attn_b, nullptr, nullptr);
  }
}